// Round 1
// baseline (278.074 us; speedup 1.0000x reference)
//
#include <hip/hip_runtime.h>

// CTC batch cost (Keras semantics): blank = C-1, full-length inputs/labels.
// Strategy: scaled linear-domain forward DP, one wave (64 lanes) per batch row.
// Lane l owns extended states s = 4l..4l+3 (+ phantom s=4l+4; real only on lane 63).
//   even s -> blank, s=4l+1 -> y_true[2l], s=4l+3 -> y_true[2l+1]
// Only cross-lane dependency per step: prev lane's a3 (state 4l-1) -> one shfl_up.
// Rescale by 2^-e every 4 steps (e from exponent bits of wave-max), accumulate e.

constexpr int   T_LEN = 1024;
constexpr int   C_DIM = 512;
constexpr int   L_LEN = 128;
constexpr int   BLANK = C_DIM - 1;
constexpr float EPSF  = 1e-7f;
constexpr float LN2F  = 0.69314718055994530942f;

__global__ __launch_bounds__(64)
void ctc_fwd_kernel(const int* __restrict__ y_true,
                    const float* __restrict__ y_hat,
                    float* __restrict__ out)
{
    const int b    = blockIdx.x;
    const int lane = threadIdx.x;

    const float* __restrict__ yb = y_hat + (size_t)b * T_LEN * C_DIM;
    const int*   __restrict__ lb = y_true + b * L_LEN;

    // labels for this lane's two odd (label) states
    const int l0 = lb[2 * lane];       // state s = 4l+1
    const int l1 = lb[2 * lane + 1];   // state s = 4l+3
    const int lpidx = (2 * lane - 1) < 0 ? 0 : (2 * lane - 1);
    const int lprev = lb[lpidx];       // label preceding l0 (garbage for lane 0, masked)

    // skip-transition allowed iff label state, label != blank, label != label two back
    const float sk1 = (lane > 0 && l0 != lprev && l0 != BLANK) ? 1.0f : 0.0f;
    const float sk3 = (l1 != l0 && l1 != BLANK) ? 1.0f : 0.0f;

    // alpha in scaled linear domain. "t = -1" init: a0=1 on lane 0 makes the
    // t=0 loop iteration produce exactly alpha0 (lp[0,s=0], lp[0,s=1], -inf...).
    float a0 = (lane == 0) ? 1.0f : 0.0f;
    float a1 = 0.0f, a2 = 0.0f, a3 = 0.0f, a4 = 0.0f;
    int   e2 = 0;  // accumulated base-2 exponent removed by rescaling

    // 4-deep software-pipelined probability loads (static indices -> registers)
    float pb[4], p1[4], p3[4];
#pragma unroll
    for (int i = 0; i < 4; ++i) {
        const float* row = yb + (size_t)i * C_DIM;
        pb[i] = row[BLANK];
        p1[i] = row[l0];
        p3[i] = row[l1];
    }

#pragma unroll 1
    for (int blk = 0; blk < T_LEN / 4; ++blk) {
#pragma unroll
        for (int i = 0; i < 4; ++i) {
            const float Pb = pb[i] + EPSF;
            const float P1 = p1[i] + EPSF;
            const float P3 = p3[i] + EPSF;

            // prefetch t + 4 (clamped; tail loads are discarded)
            int tn = blk * 4 + i + 4;
            tn = (tn < T_LEN) ? tn : (T_LEN - 1);
            const float* row = yb + (size_t)tn * C_DIM;
            pb[i] = row[BLANK];
            p1[i] = row[l0];
            p3[i] = row[l1];

            // prev lane's old a3 = alpha[4l-1]
            float pa3 = __shfl_up(a3, 1);
            pa3 = (lane == 0) ? 0.0f : pa3;

            const float n0 = Pb * (a0 + pa3);                    // even: no skip
            const float n1 = P1 * (a1 + a0 + sk1 * pa3);         // label state
            const float n2 = Pb * (a2 + a1);                     // even: no skip
            const float n3 = P3 * (a3 + a2 + sk3 * a1);          // label state
            const float n4 = Pb * (a4 + a3);                     // s=256 (real on lane 63)
            a0 = n0; a1 = n1; a2 = n2; a3 = n3; a4 = n4;
        }

        // periodic power-of-two rescale: max decay over 4 steps >= (1e-7)^4 = 2^-93
        float m = fmaxf(fmaxf(fmaxf(a0, a1), fmaxf(a2, a3)), a4);
#pragma unroll
        for (int d = 1; d < 64; d <<= 1)
            m = fmaxf(m, __shfl_xor(m, d));
        const unsigned ebits = (__float_as_uint(m) >> 23) & 0xFFu;   // m is normal > 0
        const float scale = __uint_as_float((254u - ebits) << 23);   // 2^-(e)
        e2 += (int)ebits - 127;
        a0 *= scale; a1 *= scale; a2 *= scale; a3 *= scale; a4 *= scale;
    }

    if (lane == 63) {
        // true alpha = stored * 2^e2 ; loss = -ln(alpha[255] + alpha[256])
        const float v = a3 + a4;
        out[b] = -((log2f(v) + (float)e2) * LN2F);
    }
}

extern "C" void kernel_launch(void* const* d_in, const int* in_sizes, int n_in,
                              void* d_out, int out_size, void* d_ws, size_t ws_size,
                              hipStream_t stream)
{
    const int*   y_true = (const int*)d_in[0];
    const float* y_hat  = (const float*)d_in[1];
    float*       out    = (float*)d_out;
    const int B = out_size;  // 64 rows, one wave each
    ctc_fwd_kernel<<<dim3(B), dim3(64), 0, stream>>>(y_true, y_hat, out);
}

// Round 2
// 150.523 us; speedup vs baseline: 1.8474x; 1.8474x over previous
//
#include <hip/hip_runtime.h>

// CTC batch cost (Keras semantics): blank = C-1, full-length inputs/labels.
// Two-phase:
//   Phase 1 (ctc_gather): massively-parallel compaction of the 130 needed
//     probabilities per (b,t) -> cmp[B][T][130]: [0..127]=p[label_j]+EPS in
//     extended order, [128]=p[blank]+EPS, [129]=pad. Converts the scan's
//     scattered gathers into coalesced loads.
//   Phase 2 (ctc_scan): scaled linear-domain forward DP, one wave per row.
//     Lane l owns extended states 4l..4l+3 (+phantom 4l+4, real on lane 63).
//     Per step: one coalesced float2 + one broadcast float, one shfl_up.
//     PER-LANE power-of-2 rescale (exponent int E per lane) so dynamic range
//     is unbounded -- wave-uniform scaling flushed states ~e^-100 below the
//     running max and cost ~96 log-units of error in R1.

constexpr int   B_DIM = 64;
constexpr int   T_LEN = 1024;
constexpr int   C_DIM = 512;
constexpr int   L_LEN = 128;
constexpr int   W_CMP = 130;          // compact row: 128 labels + blank + pad
constexpr int   BLANK = C_DIM - 1;
constexpr float EPSF  = 1e-7f;
constexpr float LN2F  = 0.69314718055994530942f;

__global__ __launch_bounds__(256)
void ctc_gather(const int* __restrict__ yt, const float* __restrict__ yh,
                float* __restrict__ cmp)
{
    const int id = blockIdx.x * 256 + threadIdx.x;
    constexpr int NTOT = B_DIM * T_LEN * W_CMP;
    if (id >= NTOT) return;
    const int bt = id / W_CMP;
    const int j  = id - bt * W_CMP;
    const int b  = bt >> 10;          // T_LEN = 1024
    float v = 0.0f;
    if (j < L_LEN)       v = yh[(size_t)bt * C_DIM + yt[b * L_LEN + j]] + EPSF;
    else if (j == L_LEN) v = yh[(size_t)bt * C_DIM + BLANK] + EPSF;
    cmp[id] = v;                      // coalesced write
}

template<bool COMPACT>
__global__ __launch_bounds__(64)
void ctc_scan(const int* __restrict__ yt, const float* __restrict__ src,
              float* __restrict__ out)
{
    const int b    = blockIdx.x;
    const int lane = threadIdx.x;
    const int* __restrict__ lb = yt + b * L_LEN;

    const int l0 = lb[2 * lane];                    // state 4l+1
    const int l1 = lb[2 * lane + 1];                // state 4l+3
    const int lp = lane ? lb[2 * lane - 1] : 0;
    const float sk1 = (lane > 0 && l0 != lp && l0 != BLANK) ? 1.0f : 0.0f;
    const float sk3 = (l1 != l0 && l1 != BLANK) ? 1.0f : 0.0f;

    const float* __restrict__ base =
        COMPACT ? src + (size_t)b * T_LEN * W_CMP
                : src + (size_t)b * T_LEN * C_DIM;

    // "t=-1" init: a0=1 on lane 0 makes step t=0 produce exactly alpha0.
    float a0 = (lane == 0) ? 1.0f : 0.0f;
    float a1 = 0.0f, a2 = 0.0f, a3 = 0.0f, a4 = 0.0f;
    int   E  = 0;                                   // per-lane exponent
    float sSeed = (lane == 0) ? 0.0f : 1.0f;        // 2^(E_prev - E), 0 masks lane 0

    float pb[8], p1[8], p3[8];                      // depth-8 prefetch ring
    auto LOADT = [&](int slot, int t) {
        if (COMPACT) {
            const float* row = base + (size_t)t * W_CMP;
            const float2 v = *reinterpret_cast<const float2*>(row + 2 * lane);
            p1[slot] = v.x; p3[slot] = v.y; pb[slot] = row[L_LEN];
        } else {
            const float* row = base + (size_t)t * C_DIM;
            pb[slot] = row[BLANK]; p1[slot] = row[l0]; p3[slot] = row[l1];
        }
    };
#pragma unroll
    for (int i = 0; i < 8; ++i) LOADT(i, i);

#pragma unroll 1
    for (int blk = 0; blk < T_LEN / 8; ++blk) {
#pragma unroll
        for (int half = 0; half < 2; ++half) {
#pragma unroll
            for (int i = 0; i < 4; ++i) {
                const int slot = half * 4 + i;
                float Pb, P1, P3;
                if (COMPACT) { Pb = pb[slot]; P1 = p1[slot]; P3 = p3[slot]; }
                else { Pb = pb[slot] + EPSF; P1 = p1[slot] + EPSF; P3 = p3[slot] + EPSF; }

                int tn = blk * 8 + slot + 8;        // prefetch t+8 (tail clamped)
                tn = tn < T_LEN ? tn : T_LEN - 1;
                LOADT(slot, tn);

                const float pa3 = __shfl_up(a3, 1) * sSeed;  // alpha[4l-1], rescaled
                const float n0 = Pb * (a0 + pa3);
                const float n1 = P1 * (a1 + a0 + sk1 * pa3);
                const float n2 = Pb * (a2 + a1);
                const float n3 = P3 * (a3 + a2 + sk3 * a1);
                const float n4 = Pb * (a4 + a3);
                a0 = n0; a1 = n1; a2 = n2; a3 = n3; a4 = n4;
            }
            // per-lane rescale every 4 steps (max decay >= (1e-7)^4 = 2^-93)
            const float m = fmaxf(fmaxf(fmaxf(a0, a1), fmaxf(a2, a3)), a4);
            const bool has = m > 0.0f;
            int eb = (int)((__float_as_uint(m) >> 23) & 0xFFu);
            eb = eb < 1 ? 1 : eb;                   // denormal m -> scale up
            if (has) {
                const float scl = __uint_as_float((unsigned)(254 - eb) << 23);
                a0 *= scl; a1 *= scl; a2 *= scl; a3 *= scl; a4 *= scl;
                E += eb - 127;
            }
            int pE = __shfl_up(E, 1);
            if (!has && lane > 0) E = pE;           // empty lane adopts neighbor's E
            pE = __shfl_up(E, 1);
            const int d = pE - E;
            sSeed = (lane == 0 || d < -126)
                  ? 0.0f
                  : __uint_as_float((unsigned)(127 + (d > 126 ? 126 : d)) << 23);
        }
    }

    if (lane == 63)                                 // states 255 (a3) + 256 (a4)
        out[b] = -((log2f(a3 + a4) + (float)E) * LN2F);
}

extern "C" void kernel_launch(void* const* d_in, const int* in_sizes, int n_in,
                              void* d_out, int out_size, void* d_ws, size_t ws_size,
                              hipStream_t stream)
{
    const int*   yt  = (const int*)d_in[0];
    const float* yh  = (const float*)d_in[1];
    float*       out = (float*)d_out;

    const size_t need = (size_t)B_DIM * T_LEN * W_CMP * sizeof(float);
    if (d_ws != nullptr && ws_size >= need) {
        float* cmp = (float*)d_ws;
        constexpr int NTOT = B_DIM * T_LEN * W_CMP;
        ctc_gather<<<dim3((NTOT + 255) / 256), dim3(256), 0, stream>>>(yt, yh, cmp);
        ctc_scan<true><<<dim3(B_DIM), dim3(64), 0, stream>>>(yt, cmp, out);
    } else {
        ctc_scan<false><<<dim3(B_DIM), dim3(64), 0, stream>>>(yt, yh, out);
    }
}

// Round 4
// 113.389 us; speedup vs baseline: 2.4524x; 1.3275x over previous
//
#include <hip/hip_runtime.h>

// CTC batch cost (Keras semantics): blank = C-1, full-length inputs/labels.
// Two-phase:
//   Phase 1 (ctc_gather): compacts the 130 needed probabilities per (b,t)
//     -> cmp[B][T][130]: [0..127]=p[label_j]+EPS (extended order),
//     [128]=p[blank]+EPS, [129]=pad. Turns the scan's scattered gathers into
//     coalesced loads.
//   Phase 2 (ctc_scan): scaled linear-domain forward DP, one wave per row.
//     Lane l owns extended states 4l..4l+3 (+phantom 4l+4, real on lane 63).
//     Cross-lane shift uses DPP wave_shr:1 (pure VALU, ~4 cyc) instead of
//     ds_bpermute (~120 cyc LDS latency) -- that shfl chain was 274 cyc/step
//     in R2. Per-lane power-of-2 rescale every 4 steps keeps unbounded
//     dynamic range (absmax was 0.0 with this scheme).

constexpr int   B_DIM = 64;
constexpr int   T_LEN = 1024;
constexpr int   C_DIM = 512;
constexpr int   L_LEN = 128;
constexpr int   W_CMP = 130;          // compact row: 128 labels + blank + pad
constexpr int   BLANK = C_DIM - 1;
constexpr float EPSF  = 1e-7f;
constexpr float LN2F  = 0.69314718055994530942f;

// lane l <- lane l-1, lane 0 <- 0 (DPP wave_shr:1, bound_ctrl=0-fill). VALU-only.
__device__ __forceinline__ float wshr1_f(float x) {
    return __int_as_float(__builtin_amdgcn_update_dpp(
        0, __float_as_int(x), 0x138, 0xf, 0xf, true));
}
__device__ __forceinline__ int wshr1_i(int x) {
    return __builtin_amdgcn_update_dpp(0, x, 0x138, 0xf, 0xf, true);
}

__global__ __launch_bounds__(256)
void ctc_gather(const int* __restrict__ yt, const float* __restrict__ yh,
                float* __restrict__ cmp)
{
    const int id = blockIdx.x * 256 + threadIdx.x;
    constexpr int NTOT = B_DIM * T_LEN * W_CMP;
    if (id >= NTOT) return;
    const int bt = id / W_CMP;
    const int j  = id - bt * W_CMP;
    const int b  = bt >> 10;          // T_LEN = 1024
    float v = 0.0f;
    if (j < L_LEN)       v = yh[(size_t)bt * C_DIM + yt[b * L_LEN + j]] + EPSF;
    else if (j == L_LEN) v = yh[(size_t)bt * C_DIM + BLANK] + EPSF;
    cmp[id] = v;                      // coalesced write
}

template<bool COMPACT>
__global__ __launch_bounds__(64)
void ctc_scan(const int* __restrict__ yt, const float* __restrict__ src,
              float* __restrict__ out)
{
    const int b    = blockIdx.x;
    const int lane = threadIdx.x;
    const int* __restrict__ lb = yt + b * L_LEN;

    const int l0 = lb[2 * lane];                    // state 4l+1
    const int l1 = lb[2 * lane + 1];                // state 4l+3
    const int lp = lane ? lb[2 * lane - 1] : 0;
    const float sk1 = (lane > 0 && l0 != lp && l0 != BLANK) ? 1.0f : 0.0f;
    const float sk3 = (l1 != l0 && l1 != BLANK) ? 1.0f : 0.0f;

    const float* __restrict__ base =
        COMPACT ? src + (size_t)b * T_LEN * W_CMP
                : src + (size_t)b * T_LEN * C_DIM;

    // "t=-1" init: a0=1 on lane 0 makes step t=0 produce exactly alpha0.
    float a0 = (lane == 0) ? 1.0f : 0.0f;
    float a1 = 0.0f, a2 = 0.0f, a3 = 0.0f, a4 = 0.0f;
    int   E  = 0;                                   // per-lane exponent
    float sSeed = (lane == 0) ? 0.0f : 1.0f;        // 2^(E_prev - E), 0 masks lane 0

    constexpr int DEPTH = 16;                       // load ring (covers ~L2 latency)
    float pb[DEPTH], p1[DEPTH], p3[DEPTH];
    auto LOADT = [&](int slot, int t) {
        if (COMPACT) {
            const float* row = base + (size_t)t * W_CMP;
            const float2 v = *reinterpret_cast<const float2*>(row + 2 * lane);
            p1[slot] = v.x; p3[slot] = v.y; pb[slot] = row[L_LEN];
        } else {
            const float* row = base + (size_t)t * C_DIM;
            pb[slot] = row[BLANK]; p1[slot] = row[l0]; p3[slot] = row[l1];
        }
    };
#pragma unroll
    for (int i = 0; i < DEPTH; ++i) LOADT(i, i);

#pragma unroll 1
    for (int blk = 0; blk < T_LEN / DEPTH; ++blk) {
#pragma unroll
        for (int q = 0; q < DEPTH / 4; ++q) {
#pragma unroll
            for (int i = 0; i < 4; ++i) {
                const int slot = q * 4 + i;
                float Pb, P1, P3;
                if (COMPACT) { Pb = pb[slot]; P1 = p1[slot]; P3 = p3[slot]; }
                else { Pb = pb[slot] + EPSF; P1 = p1[slot] + EPSF; P3 = p3[slot] + EPSF; }

                int tn = blk * DEPTH + slot + DEPTH;      // prefetch t+DEPTH
                tn = tn < T_LEN ? tn : T_LEN - 1;         // (tail clamped)
                LOADT(slot, tn);

                const float pa3 = wshr1_f(a3) * sSeed;    // alpha[4l-1], rescaled
                const float n0 = Pb * (a0 + pa3);
                const float n1 = P1 * (a1 + a0 + sk1 * pa3);
                const float n2 = Pb * (a2 + a1);
                const float n3 = P3 * (a3 + a2 + sk3 * a1);
                const float n4 = Pb * (a4 + a3);
                a0 = n0; a1 = n1; a2 = n2; a3 = n3; a4 = n4;
            }
            // per-lane rescale every 4 steps (max decay >= (1e-7)^4 = 2^-93)
            const float m = fmaxf(fmaxf(fmaxf(a0, a1), fmaxf(a2, a3)), a4);
            const bool has = m > 0.0f;
            int eb = (int)((__float_as_uint(m) >> 23) & 0xFFu);
            eb = eb < 1 ? 1 : eb;                   // denormal m -> scale up
            if (has) {
                const float scl = __uint_as_float((unsigned)(254 - eb) << 23);
                a0 *= scl; a1 *= scl; a2 *= scl; a3 *= scl; a4 *= scl;
                E += eb - 127;
            }
            int pE = wshr1_i(E);
            if (!has && lane > 0) E = pE;           // empty lane adopts neighbor's E
            pE = wshr1_i(E);
            const int d = pE - E;
            sSeed = (lane == 0 || d < -126)
                  ? 0.0f
                  : __uint_as_float((unsigned)(127 + (d > 126 ? 126 : d)) << 23);
        }
    }

    if (lane == 63)                                 // states 255 (a3) + 256 (a4)
        out[b] = -((log2f(a3 + a4) + (float)E) * LN2F);
}

extern "C" void kernel_launch(void* const* d_in, const int* in_sizes, int n_in,
                              void* d_out, int out_size, void* d_ws, size_t ws_size,
                              hipStream_t stream)
{
    const int*   yt  = (const int*)d_in[0];
    const float* yh  = (const float*)d_in[1];
    float*       out = (float*)d_out;

    const size_t need = (size_t)B_DIM * T_LEN * W_CMP * sizeof(float);
    if (d_ws != nullptr && ws_size >= need) {
        float* cmp = (float*)d_ws;
        constexpr int NTOT = B_DIM * T_LEN * W_CMP;
        ctc_gather<<<dim3((NTOT + 255) / 256), dim3(256), 0, stream>>>(yt, yh, cmp);
        ctc_scan<true><<<dim3(B_DIM), dim3(64), 0, stream>>>(yt, cmp, out);
    } else {
        ctc_scan<false><<<dim3(B_DIM), dim3(64), 0, stream>>>(yt, yh, out);
    }
}

// Round 5
// 105.630 us; speedup vs baseline: 2.6325x; 1.0735x over previous
//
#include <hip/hip_runtime.h>

// CTC batch cost (Keras semantics): blank = C-1, full-length inputs/labels.
// Two-phase:
//   Phase 1 (ctc_gather): compacts the 130 needed probabilities per (b,t)
//     -> cmp[B][T][130]: [0..127]=p[label_j]+EPS (extended order),
//     [128]=[129]=p[blank]+EPS (replicated so the scan's blank load is
//     LANE-DEPENDENT -> VMEM, not SMEM). Coalesced writes.
//   Phase 2 (ctc_scan): scaled linear-domain forward DP, one wave per row.
//     Lane l owns extended states 4l..4l+3 (+phantom 4l+4, real on lane 63).
//     Cross-lane shift via DPP wave_shr:1 (VALU-only). Per-lane power-of-2
//     rescale every 4 steps (unbounded dynamic range; absmax 0.0 in R2/R4).
//   R4 lesson: the wave-uniform blank load row[128] became an s_load; SMEM
//     returns out-of-order so each use forced lgkmcnt(0), draining the whole
//     prefetch ring -> ~190 cyc/step. lane-dependent address keeps all loads
//     on the in-order vmcnt path so the 16-deep ring actually pipelines.

constexpr int   B_DIM = 64;
constexpr int   T_LEN = 1024;
constexpr int   C_DIM = 512;
constexpr int   L_LEN = 128;
constexpr int   W_CMP = 130;          // 128 labels + blank x2 (replicated)
constexpr int   BLANK = C_DIM - 1;
constexpr float EPSF  = 1e-7f;
constexpr float LN2F  = 0.69314718055994530942f;

// lane l <- lane l-1, lane 0 <- 0 (DPP wave_shr:1, bound_ctrl=0-fill). VALU-only.
__device__ __forceinline__ float wshr1_f(float x) {
    return __int_as_float(__builtin_amdgcn_update_dpp(
        0, __float_as_int(x), 0x138, 0xf, 0xf, true));
}
__device__ __forceinline__ int wshr1_i(int x) {
    return __builtin_amdgcn_update_dpp(0, x, 0x138, 0xf, 0xf, true);
}

__global__ __launch_bounds__(256)
void ctc_gather(const int* __restrict__ yt, const float* __restrict__ yh,
                float* __restrict__ cmp)
{
    const int id = blockIdx.x * 256 + threadIdx.x;
    constexpr int NTOT = B_DIM * T_LEN * W_CMP;
    if (id >= NTOT) return;
    const int bt = id / W_CMP;
    const int j  = id - bt * W_CMP;
    const int b  = bt >> 10;          // T_LEN = 1024
    float v;
    if (j < L_LEN) v = yh[(size_t)bt * C_DIM + yt[b * L_LEN + j]] + EPSF;
    else           v = yh[(size_t)bt * C_DIM + BLANK] + EPSF;   // j = 128, 129
    cmp[id] = v;                      // coalesced write
}

template<bool COMPACT>
__global__ __launch_bounds__(64)
void ctc_scan(const int* __restrict__ yt, const float* __restrict__ src,
              float* __restrict__ out)
{
    const int b    = blockIdx.x;
    const int lane = threadIdx.x;
    const int* __restrict__ lb = yt + b * L_LEN;

    const int l0 = lb[2 * lane];                    // state 4l+1
    const int l1 = lb[2 * lane + 1];                // state 4l+3
    const int lp = lane ? lb[2 * lane - 1] : 0;
    const float sk1 = (lane > 0 && l0 != lp && l0 != BLANK) ? 1.0f : 0.0f;
    const float sk3 = (l1 != l0 && l1 != BLANK) ? 1.0f : 0.0f;

    const float* __restrict__ base =
        COMPACT ? src + (size_t)b * T_LEN * W_CMP
                : src + (size_t)b * T_LEN * C_DIM;

    // "t=-1" init: a0=1 on lane 0 makes step t=0 produce exactly alpha0.
    float a0 = (lane == 0) ? 1.0f : 0.0f;
    float a1 = 0.0f, a2 = 0.0f, a3 = 0.0f, a4 = 0.0f;
    int   E  = 0;                                   // per-lane exponent
    float sSeed = (lane == 0) ? 0.0f : 1.0f;        // 2^(E_prev - E), 0 masks lane 0

    constexpr int DEPTH = 16;                       // load ring (covers L2/L3 latency)
    float pb[DEPTH], p1[DEPTH], p3[DEPTH];
    const int bsel = L_LEN + (lane & 1);            // lane-dependent blank slot
    auto LOADT = [&](int slot, int t) {
        if (COMPACT) {
            const float* row = base + (size_t)t * W_CMP;
            const float2 v = *reinterpret_cast<const float2*>(row + 2 * lane);
            p1[slot] = v.x; p3[slot] = v.y;
            pb[slot] = row[bsel];                   // VMEM (lane-varying addr)
        } else {
            const float* row = base + (size_t)t * C_DIM;
            pb[slot] = row[BLANK]; p1[slot] = row[l0]; p3[slot] = row[l1];
        }
    };
#pragma unroll
    for (int i = 0; i < DEPTH; ++i) LOADT(i, i);

#pragma unroll 1
    for (int blk = 0; blk < T_LEN / DEPTH; ++blk) {
#pragma unroll
        for (int q = 0; q < DEPTH / 4; ++q) {
#pragma unroll
            for (int i = 0; i < 4; ++i) {
                const int slot = q * 4 + i;
                float Pb, P1, P3;
                if (COMPACT) { Pb = pb[slot]; P1 = p1[slot]; P3 = p3[slot]; }
                else { Pb = pb[slot] + EPSF; P1 = p1[slot] + EPSF; P3 = p3[slot] + EPSF; }

                int tn = blk * DEPTH + slot + DEPTH;      // prefetch t+DEPTH
                tn = tn < T_LEN ? tn : T_LEN - 1;         // (tail clamped)
                LOADT(slot, tn);

                const float pa3 = wshr1_f(a3) * sSeed;    // alpha[4l-1], rescaled
                const float n0 = Pb * (a0 + pa3);
                const float n1 = P1 * (a1 + a0 + sk1 * pa3);
                const float n2 = Pb * (a2 + a1);
                const float n3 = P3 * (a3 + a2 + sk3 * a1);
                const float n4 = Pb * (a4 + a3);
                a0 = n0; a1 = n1; a2 = n2; a3 = n3; a4 = n4;
            }
            // per-lane rescale every 4 steps (max decay >= (1e-7)^4 = 2^-93)
            const float m = fmaxf(fmaxf(fmaxf(a0, a1), fmaxf(a2, a3)), a4);
            const bool has = m > 0.0f;
            int eb = (int)((__float_as_uint(m) >> 23) & 0xFFu);
            eb = eb < 1 ? 1 : eb;                   // denormal m -> scale up
            if (has) {
                const float scl = __uint_as_float((unsigned)(254 - eb) << 23);
                a0 *= scl; a1 *= scl; a2 *= scl; a3 *= scl; a4 *= scl;
                E += eb - 127;
            }
            int pE = wshr1_i(E);
            if (!has && lane > 0) E = pE;           // empty lane adopts neighbor's E
            pE = wshr1_i(E);
            const int d = pE - E;
            sSeed = (lane == 0 || d < -126)
                  ? 0.0f
                  : __uint_as_float((unsigned)(127 + (d > 126 ? 126 : d)) << 23);
        }
    }

    if (lane == 63)                                 // states 255 (a3) + 256 (a4)
        out[b] = -((log2f(a3 + a4) + (float)E) * LN2F);
}

extern "C" void kernel_launch(void* const* d_in, const int* in_sizes, int n_in,
                              void* d_out, int out_size, void* d_ws, size_t ws_size,
                              hipStream_t stream)
{
    const int*   yt  = (const int*)d_in[0];
    const float* yh  = (const float*)d_in[1];
    float*       out = (float*)d_out;

    const size_t need = (size_t)B_DIM * T_LEN * W_CMP * sizeof(float);
    if (d_ws != nullptr && ws_size >= need) {
        float* cmp = (float*)d_ws;
        constexpr int NTOT = B_DIM * T_LEN * W_CMP;
        ctc_gather<<<dim3((NTOT + 255) / 256), dim3(256), 0, stream>>>(yt, yh, cmp);
        ctc_scan<true><<<dim3(B_DIM), dim3(64), 0, stream>>>(yt, cmp, out);
    } else {
        ctc_scan<false><<<dim3(B_DIM), dim3(64), 0, stream>>>(yt, yh, out);
    }
}